// Round 5
// baseline (491.142 us; speedup 1.0000x reference)
//
#include <hip/hip_runtime.h>
#include <math.h>

// Shift_11261404250938: per-image shift(trunc(±10%)) + zero-fill, standardize,
// min-max normalize. Standardization cancels in the min-max step, so
// out = (shifted - min) / (max - min).
//
// R6 -> R7: six structural variants all pinned at ~117us / 2.5 TB/s with
// traffic at the floor and VALU/occupancy proven non-limiters (R6: VALUBusy
// 17.5->5.7%, dur unchanged). Remaining mechanism: MACHINE-WIDE PHASE
// SERIALIZATION -- all blocks read (phase 1) in lockstep, barrier, then all
// write (phase 2); read and write streams never overlap (copy/fill kernels
// that mix them hit 6.3-6.6 TB/s). R7 overlaps them via producer/consumer:
//  - 128 producer blocks: chain of 2 images each (r, then r+128) -> images
//    0..127 published at the half-way point (the stagger).
//  - 256 consumer blocks: one image each; tid0 spins on an agent-scope flag,
//    then runs the verified R6 phase-2 gather.
//  - All 384 blocks (512 thr, 8 waves) co-resident by capacity -> spin is
//    safe; producers are blockIdx 0..127 (dispatched first) anyway.
//  - Flags zeroed by 1KB hipMemsetAsync (graph-capture-safe, replayed).
// Phase-1/phase-2 bodies are the R6-verified row-wise forms (WVB=8, RPW=84).

constexpr int kC = 3, kH = 224, kW = 224;
constexpr int kCHW  = kC * kH * kW;  // 150528
constexpr int kROWS = kC * kH;       // 672
constexpr int kQPR  = kW / 4;        // 56 quads per row
constexpr int TB    = 512;           // 8 waves
constexpr int WVB   = TB / 64;       // 8
constexpr int RPW   = kROWS / WVB;   // 84 rows per wave (exact)

typedef float f32x4 __attribute__((ext_vector_type(4)));

__device__ __forceinline__ void shifts_for(const float* __restrict__ sfy,
                                           const float* __restrict__ sfx,
                                           int img, int& sy, int& sx)
{
    // Replicate reference fp32 order: ((f*2-1)*0.1f)*size, trunc toward zero.
    float ty = sfy[img] * 2.0f - 1.0f; ty *= 0.1f; ty *= (float)kH;
    sy = (int)truncf(ty);
    float tx = sfx[img] * 2.0f - 1.0f; tx *= 0.1f; tx *= (float)kW;
    sx = (int)truncf(tx);
}

// R6-verified row-wise min/max: lane = column-quad (lanes 56-63 idle), wave
// walks rows stride WVB; column masks loop-invariant; zero-seed covers all
// artificial zeros when any shift != 0; invalid source rows skipped.
__device__ __forceinline__ void minmax_image(const float* __restrict__ xb,
                                             int sy, int sx, int lane, int wv,
                                             float& omn, float& omx)
{
    const int rlo = sy > 0 ? sy : 0;
    const int rhi = kH + (sy < 0 ? sy : 0);
    const int clo = sx > 0 ? sx : 0;
    const int chi = kW + (sx < 0 ? sx : 0);

    const bool hasfill = (sy != 0) | (sx != 0);
    float vmin = hasfill ? 0.0f : INFINITY;
    float vmax = hasfill ? 0.0f : -INFINITY;

    if (lane < kQPR) {
        const int i0 = lane * 4;
        float cm[4];
        #pragma unroll
        for (int k = 0; k < 4; ++k)
            cm[k] = ((i0 + k) >= clo && (i0 + k) < chi) ? 1.0f : 0.0f;

        #pragma unroll 6
        for (int t = 0; t < RPW; ++t) {
            const int rr = wv + t * WVB;          // row in [0, C*H)
            const int j  = rr % kH;               // wave-uniform scalar
            if (j >= rlo && j < rhi) {            // skip invalid source rows
                const f32x4 v = *(const f32x4*)(xb + rr * kW + i0);
                #pragma unroll
                for (int k = 0; k < 4; ++k) {
                    const float val = v[k] * cm[k];  // invalid col -> 0 (legal)
                    vmin = fminf(vmin, val);
                    vmax = fmaxf(vmax, val);
                }
            }
        }
    }
    #pragma unroll
    for (int off = 32; off > 0; off >>= 1) {
        vmin = fminf(vmin, __shfl_down(vmin, off));
        vmax = fmaxf(vmax, __shfl_down(vmax, off));
    }
    omn = vmin; omx = vmax;
}

// R6-verified gather: two aligned float4 loads + compile-time rotate
// (R = sx & 3; bases are multiples of 4 so clamped lanes' wrong elements are
// always masked); invalid dest rows -> splat((0-mn)*inv), no loads.
template <int R>
__device__ __forceinline__ void phase2_rows(const float* __restrict__ xb,
                                            float* __restrict__ ob,
                                            int sy, int sx, float inv,
                                            float zoff, int wv, int lane)
{
    if (lane >= kQPR) return;
    const int i0   = lane * 4;
    const int base = i0 + sx - R;                  // multiple of 4
    int qa = base;     qa = qa < 0 ? 0 : qa; qa = qa > kW - 4 ? kW - 4 : qa;
    int qb = base + 4; qb = qb < 0 ? 0 : qb; qb = qb > kW - 4 ? kW - 4 : qb;

    float cm[4];
    #pragma unroll
    for (int k = 0; k < 4; ++k)
        cm[k] = ((unsigned)(i0 + k + sx) < (unsigned)kW) ? 1.0f : 0.0f;
    const f32x4 zq = {zoff, zoff, zoff, zoff};

    #pragma unroll 3
    for (int t = 0; t < RPW; ++t) {
        const int rr = wv + t * WVB;               // output row in [0, C*H)
        const int j  = rr % kH;                    // wave-uniform scalar
        const int jj = j + sy;
        float* __restrict__ dst = ob + rr * kW + i0;
        if ((unsigned)jj < (unsigned)kH) {         // wave-uniform branch
            const float* __restrict__ src = xb + (rr - j + jj) * kW;
            const f32x4 av = *(const f32x4*)(src + qa);
            const f32x4 bv = *(const f32x4*)(src + qb);
            f32x4 o;
            #pragma unroll
            for (int k = 0; k < 4; ++k) {
                const float sel = (k + R < 4) ? av[k + R] : bv[k + R - 4];
                o[k] = fmaf(sel * cm[k], inv, zoff); // invalid -> (0-mn)*inv
            }
            *(f32x4*)dst = o;                      // 16B aligned
        } else {
            *(f32x4*)dst = zq;                     // zero-filled row
        }
    }
}

__global__ __launch_bounds__(TB) void shift_pipe(
    const float* __restrict__ x, const float* __restrict__ sfy,
    const float* __restrict__ sfx, float* __restrict__ out,
    unsigned* __restrict__ flag, unsigned* __restrict__ mnb,
    unsigned* __restrict__ mxb, int B, int HALF)
{
    const int bid  = blockIdx.x;
    const int tid  = threadIdx.x;
    const int lane = tid & 63;
    const int wv   = __builtin_amdgcn_readfirstlane(tid >> 6); // wave-uniform

    __shared__ float smin[WVB], smax[WVB];
    __shared__ float s_a, s_b;

    if (bid < HALF) {
        // ---------------- producer: chain of 2 images ----------------
        #pragma unroll 1
        for (int c = 0; c < 2; ++c) {
            const int img = bid + c * HALF;
            if (img >= B) break;
            const float* __restrict__ xb = x + (size_t)img * kCHW;
            int sy, sx; shifts_for(sfy, sfx, img, sy, sx);

            float vmin, vmax;
            minmax_image(xb, sy, sx, lane, wv, vmin, vmax);
            if (lane == 0) { smin[wv] = vmin; smax[wv] = vmax; }
            __syncthreads();
            if (tid == 0) {
                float mn = smin[0], mx = smax[0];
                #pragma unroll
                for (int w = 1; w < WVB; ++w) {
                    mn = fminf(mn, smin[w]);
                    mx = fmaxf(mx, smax[w]);
                }
                // payload (agent-scope), then release flag (agent-scope)
                __hip_atomic_store(&mnb[img], __float_as_uint(mn),
                                   __ATOMIC_RELAXED, __HIP_MEMORY_SCOPE_AGENT);
                __hip_atomic_store(&mxb[img], __float_as_uint(mx),
                                   __ATOMIC_RELAXED, __HIP_MEMORY_SCOPE_AGENT);
                __hip_atomic_store(&flag[img], 1u,
                                   __ATOMIC_RELEASE, __HIP_MEMORY_SCOPE_AGENT);
            }
            __syncthreads();   // smin/smax reuse safety for c=1
        }
    } else {
        // ---------------- consumer: one image ----------------
        const int img = bid - HALF;
        if (img >= B) return;
        const float* __restrict__ xb = x + (size_t)img * kCHW;
        float* __restrict__ ob = out + (size_t)img * kCHW;
        int sy, sx; shifts_for(sfy, sfx, img, sy, sx);

        if (tid == 0) {
            while (__hip_atomic_load(&flag[img], __ATOMIC_ACQUIRE,
                                     __HIP_MEMORY_SCOPE_AGENT) == 0u)
                __builtin_amdgcn_s_sleep(2);
            const float mn = __uint_as_float(
                __hip_atomic_load(&mnb[img], __ATOMIC_RELAXED,
                                  __HIP_MEMORY_SCOPE_AGENT));
            const float mx = __uint_as_float(
                __hip_atomic_load(&mxb[img], __ATOMIC_RELAXED,
                                  __HIP_MEMORY_SCOPE_AGENT));
            s_a = mn;
            s_b = 1.0f / (mx - mn);
        }
        __syncthreads();
        const float mn   = s_a;
        const float inv  = s_b;
        const float zoff = (0.0f - mn) * inv;

        switch (sx & 3) {
            case 0: phase2_rows<0>(xb, ob, sy, sx, inv, zoff, wv, lane); break;
            case 1: phase2_rows<1>(xb, ob, sy, sx, inv, zoff, wv, lane); break;
            case 2: phase2_rows<2>(xb, ob, sy, sx, inv, zoff, wv, lane); break;
            default: phase2_rows<3>(xb, ob, sy, sx, inv, zoff, wv, lane); break;
        }
    }
}

extern "C" void kernel_launch(void* const* d_in, const int* in_sizes, int n_in,
                              void* d_out, int out_size, void* d_ws, size_t ws_size,
                              hipStream_t stream) {
    const float* x  = (const float*)d_in[0];
    const float* fy = (const float*)d_in[1];
    const float* fx = (const float*)d_in[2];
    float* out = (float*)d_out;
    const int B = in_sizes[1];          // shift_fy has one element per image
    const int HALF = (B + 1) / 2;

    unsigned* flag = (unsigned*)d_ws;   // [B] flags
    unsigned* mnb  = flag + B;          // [B] min bits
    unsigned* mxb  = mnb + B;           // [B] max bits
    hipMemsetAsync(d_ws, 0, (size_t)B * sizeof(unsigned), stream);  // flags only

    shift_pipe<<<HALF + B, TB, 0, stream>>>(x, fy, fx, out, flag, mnb, mxb, B, HALF);
}

// Round 6
// 299.515 us; speedup vs baseline: 1.6398x; 1.6398x over previous
//
#include <hip/hip_runtime.h>
#include <math.h>

// Shift_11261404250938: per-image shift(trunc(±10%)) + zero-fill, standardize,
// min-max normalize. Standardization cancels in the min-max step, so
// out = (shifted - min) / (max - min).
//
// R7 -> R8: producer/consumer regressed (322us): stagger halved the active
// read stream. Root cause candidate for the universal ~117us/2.5TB/s plateau
// is now MLP DEPTH ~1: VGPR_Count=16 in every fused round means one
// outstanding float4 load per thread (addr -> load -> vmcnt(0) -> consume).
// 1KB/wave in flight x ~12 waves/CU / ~900cy HBM latency ~= 13 B/cy/CU
// ~= 2.6 TB/s chip-wide == the measured plateau, in every structure.
// R8 = R6 fused kernel + ONE change: explicit 8-deep batched loads in both
// phases (register arrays, no branches between loads; row masks are
// wave-uniform multipliers/selects -- R5-verified branchless forms).
//  - phase 1: 5 batches x 8 rows (32 data VGPRs, 8KB/wave in flight) + tail 2.
//  - phase 2: 10 batches x 4 rows (8 loads av/bv) + tail 2; invalid dest rows
//    via clamped src row + scale=0 (loads unconditional, result masked).
// Predicted: VGPR 16->45-64, kernel 117->55-80us, else falsify MLP theory.

constexpr int kC = 3, kH = 224, kW = 224;
constexpr int kCHW  = kC * kH * kW;  // 150528
constexpr int kROWS = kC * kH;       // 672
constexpr int kQPR  = kW / 4;        // 56 quads per row
constexpr int TB    = 1024;          // 16 waves
constexpr int WVB   = TB / 64;       // 16
constexpr int RPW   = kROWS / WVB;   // 42 rows per wave (exact)

typedef float f32x4 __attribute__((ext_vector_type(4)));

// ---- phase-1 batch: NB back-to-back row loads, then masked min/max ----
template <int NB>
__device__ __forceinline__ void p1_batch(const float* __restrict__ xb,
                                         int t0, int wv, int i0,
                                         const float* cm, int rlo, int rhi,
                                         float& vmin, float& vmax)
{
    f32x4 v[NB];
    #pragma unroll
    for (int u = 0; u < NB; ++u) {
        const int rr = wv + (t0 + u) * WVB;       // row in [0, C*H)
        v[u] = *(const f32x4*)(xb + rr * kW + i0);
    }
    #pragma unroll
    for (int u = 0; u < NB; ++u) {
        const int rr = wv + (t0 + u) * WVB;
        const int j  = rr % kH;                   // wave-uniform scalar
        const float srm = (j >= rlo && j < rhi) ? 1.0f : 0.0f;
        #pragma unroll
        for (int k = 0; k < 4; ++k) {
            const float val = v[u][k] * cm[k] * srm;  // invalid -> 0 (legal)
            vmin = fminf(vmin, val);
            vmax = fmaxf(vmax, val);
        }
    }
}

// ---- phase-2 batch: NB rows, 2*NB back-to-back loads, rotate+mask+store ----
// Misaligned-by-sx gather: two aligned float4 loads + compile-time rotate
// (R = sx & 3; bases multiple of 4 -> clamped lanes' wrong elems always
// masked). Invalid dest rows: clamped src row (j, in-range) + scale=0.
template <int NB, int R>
__device__ __forceinline__ void p2_batch(const float* __restrict__ xb,
                                         float* __restrict__ ob,
                                         int t0, int wv, int i0, int qa, int qb,
                                         const float* cm, int sy,
                                         float inv, float zoff)
{
    f32x4 av[NB], bv[NB];
    #pragma unroll
    for (int u = 0; u < NB; ++u) {
        const int rr = wv + (t0 + u) * WVB;       // output row in [0, C*H)
        const int j  = rr % kH;                   // wave-uniform scalar
        const int jj = j + sy;
        const int jc = ((unsigned)jj < (unsigned)kH) ? jj : j;  // in-range clamp
        const float* __restrict__ src = xb + (rr - j + jc) * kW;
        av[u] = *(const f32x4*)(src + qa);
        bv[u] = *(const f32x4*)(src + qb);
    }
    #pragma unroll
    for (int u = 0; u < NB; ++u) {
        const int rr = wv + (t0 + u) * WVB;
        const int j  = rr % kH;
        const int jj = j + sy;
        const float scale = ((unsigned)jj < (unsigned)kH) ? inv : 0.0f;
        f32x4 o;
        #pragma unroll
        for (int k = 0; k < 4; ++k) {
            const float sel = (k + R < 4) ? av[u][k + R] : bv[u][k + R - 4];
            o[k] = fmaf(sel * cm[k], scale, zoff);  // invalid -> (0-mn)*inv
        }
        *(f32x4*)(ob + rr * kW + i0) = o;         // 16B aligned
    }
}

template <int R>
__device__ __forceinline__ void phase2(const float* __restrict__ xb,
                                       float* __restrict__ ob,
                                       int sy, int sx, float inv, float zoff,
                                       int wv, int lane)
{
    if (lane >= kQPR) return;
    const int i0   = lane * 4;
    const int base = i0 + sx - R;                  // multiple of 4
    int qa = base;     qa = qa < 0 ? 0 : qa; qa = qa > kW - 4 ? kW - 4 : qa;
    int qb = base + 4; qb = qb < 0 ? 0 : qb; qb = qb > kW - 4 ? kW - 4 : qb;

    float cm[4];
    #pragma unroll
    for (int k = 0; k < 4; ++k)
        cm[k] = ((unsigned)(i0 + k + sx) < (unsigned)kW) ? 1.0f : 0.0f;

    for (int t0 = 0; t0 < RPW - 2; t0 += 4)        // 10 batches of 4
        p2_batch<4, R>(xb, ob, t0, wv, i0, qa, qb, cm, sy, inv, zoff);
    p2_batch<2, R>(xb, ob, RPW - 2, wv, i0, qa, qb, cm, sy, inv, zoff);
}

__global__ __launch_bounds__(TB) void shift_norm(
    const float* __restrict__ x, const float* __restrict__ sfy,
    const float* __restrict__ sfx, float* __restrict__ out)
{
    const int img = blockIdx.x;
    const float* __restrict__ xb = x + (size_t)img * kCHW;
    float* __restrict__ ob = out + (size_t)img * kCHW;

    // Replicate reference fp32 order: ((f*2-1)*0.1f)*size, trunc toward zero.
    float ty = sfy[img] * 2.0f - 1.0f; ty *= 0.1f; ty *= (float)kH;
    const int sy = (int)truncf(ty);
    float tx = sfx[img] * 2.0f - 1.0f; tx *= 0.1f; tx *= (float)kW;
    const int sx = (int)truncf(tx);

    // Valid input sub-rectangle (rows/cols of x that survive the shift).
    const int rlo = sy > 0 ? sy : 0;
    const int rhi = kH + (sy < 0 ? sy : 0);
    const int clo = sx > 0 ? sx : 0;
    const int chi = kW + (sx < 0 ? sx : 0);

    const int tid  = threadIdx.x;
    const int lane = tid & 63;
    const int wv   = __builtin_amdgcn_readfirstlane(tid >> 6); // wave-uniform

    // Any nonzero shift introduces zero-fill -> 0 is in the value set, which
    // covers every multiplier-masked (invalid) element's 0 contribution.
    const bool hasfill = (sy != 0) | (sx != 0);
    float vmin = hasfill ? 0.0f : INFINITY;
    float vmax = hasfill ? 0.0f : -INFINITY;

    // ---------------- Phase 1: batched row-wise min/max ----------------
    if (lane < kQPR) {
        const int i0 = lane * 4;
        float cm[4];                      // loop-invariant column validity
        #pragma unroll
        for (int k = 0; k < 4; ++k)
            cm[k] = ((i0 + k) >= clo && (i0 + k) < chi) ? 1.0f : 0.0f;

        for (int t0 = 0; t0 < RPW - 2; t0 += 8)    // 5 batches of 8
            p1_batch<8>(xb, t0, wv, i0, cm, rlo, rhi, vmin, vmax);
        p1_batch<2>(xb, RPW - 2, wv, i0, cm, rlo, rhi, vmin, vmax);
    }

    // Wave (64-lane) shuffle reduction, then cross-wave via LDS.
    #pragma unroll
    for (int off = 32; off > 0; off >>= 1) {
        vmin = fminf(vmin, __shfl_down(vmin, off));
        vmax = fmaxf(vmax, __shfl_down(vmax, off));
    }
    __shared__ float smin[WVB], smax[WVB];
    __shared__ float s_mn, s_inv;
    if (lane == 0) { smin[tid >> 6] = vmin; smax[tid >> 6] = vmax; }
    __syncthreads();
    if (tid == 0) {
        float mn = smin[0], mx = smax[0];
        #pragma unroll
        for (int w = 1; w < WVB; ++w) {
            mn = fminf(mn, smin[w]);
            mx = fmaxf(mx, smax[w]);
        }
        s_mn  = mn;
        s_inv = 1.0f / (mx - mn);
    }
    __syncthreads();
    const float mn   = s_mn;
    const float inv  = s_inv;
    const float zoff = (0.0f - mn) * inv;

    // ---------------- Phase 2: batched gather + normalize + store ----------------
    switch (sx & 3) {
        case 0: phase2<0>(xb, ob, sy, sx, inv, zoff, wv, lane); break;
        case 1: phase2<1>(xb, ob, sy, sx, inv, zoff, wv, lane); break;
        case 2: phase2<2>(xb, ob, sy, sx, inv, zoff, wv, lane); break;
        default: phase2<3>(xb, ob, sy, sx, inv, zoff, wv, lane); break;
    }
}

extern "C" void kernel_launch(void* const* d_in, const int* in_sizes, int n_in,
                              void* d_out, int out_size, void* d_ws, size_t ws_size,
                              hipStream_t stream) {
    const float* x  = (const float*)d_in[0];
    const float* fy = (const float*)d_in[1];
    const float* fx = (const float*)d_in[2];
    float* out = (float*)d_out;
    const int B = in_sizes[1];  // shift_fy has one element per image
    shift_norm<<<B, TB, 0, stream>>>(x, fy, fx, out);
}

// Round 7
// 295.783 us; speedup vs baseline: 1.6605x; 1.0126x over previous
//
#include <hip/hip_runtime.h>
#include <math.h>

// Shift_11261404250938: per-image shift(trunc(±10%)) + zero-fill, standardize,
// min-max normalize. Standardization cancels in the min-max step, so
// out = (shifted - min) / (max - min).
//
// R8 -> R9: batching (VGPR 16->32) didn't move 117us -> latency/MLP theory
// dead. Surviving theory: PER-CU VMEM BYTE THROUGHPUT CAP ~10 B/cy/CU
// (~25 GB/s/CU), counting all vector-memory traffic regardless of hit level:
//   fill 6.6 TB/s/256CU = 25.8 GB/s/CU (at cap), copy 6.29 = 24.6 (at cap),
//   ours: 588KB(p1 rd) + 2x588KB(p2 dual gather loads, L3-hit but still
//   through TA/TCP) + 588KB(st) = 2.35MB/CU -> 94-117us AT THE CAP.
// R9 = ONE change vs R8: eliminate phase-2's second load. After ONE aligned
// load per lane, src quads q+s4 and q+s4+1 live in neighbor lanes' registers;
// gather via 4 ds_bpermute (__shfl, wave-uniform lane delta) per quad:
//   sel[k] = shfl(v[(k+R)&3], lane + s4 + (k+R>=4)),  s4=(sx-R)/4, R=sx&3.
// Out-of-range shuffles return garbage exactly where cm[k] masks (invalid
// source cols) -- invariant verified since R2. Phase-2 VMEM: 48 -> 32 B/quad.
// Predicted: kernel 117 -> 85-95us with FETCH/WRITE UNCHANGED (removed loads
// were L3 hits -- the discriminating signature of the byte-cap theory).

constexpr int kC = 3, kH = 224, kW = 224;
constexpr int kCHW  = kC * kH * kW;  // 150528
constexpr int kROWS = kC * kH;       // 672
constexpr int kQPR  = kW / 4;        // 56 quads per row
constexpr int TB    = 1024;          // 16 waves
constexpr int WVB   = TB / 64;       // 16
constexpr int RPW   = kROWS / WVB;   // 42 rows per wave (exact)

typedef float f32x4 __attribute__((ext_vector_type(4)));

// ---- phase-1 batch: NB back-to-back row loads, then masked min/max ----
template <int NB>
__device__ __forceinline__ void p1_batch(const float* __restrict__ xb,
                                         int t0, int wv, int i0,
                                         const float* cm, int rlo, int rhi,
                                         float& vmin, float& vmax)
{
    f32x4 v[NB];
    #pragma unroll
    for (int u = 0; u < NB; ++u) {
        const int rr = wv + (t0 + u) * WVB;       // row in [0, C*H)
        v[u] = *(const f32x4*)(xb + rr * kW + i0);
    }
    #pragma unroll
    for (int u = 0; u < NB; ++u) {
        const int rr = wv + (t0 + u) * WVB;
        const int j  = rr % kH;                   // wave-uniform scalar
        const float srm = (j >= rlo && j < rhi) ? 1.0f : 0.0f;
        #pragma unroll
        for (int k = 0; k < 4; ++k) {
            const float val = v[u][k] * cm[k] * srm;  // invalid -> 0 (legal)
            vmin = fminf(vmin, val);
            vmax = fmaxf(vmax, val);
        }
    }
}

// ---- phase-2 batch: NB rows, NB loads, shuffle-gather + mask + store ----
// One aligned 16B load per lane per row (lane's OWN column quad of the
// shifted source row), then pull quads q+s4 / q+s4+1 from neighbor lanes via
// __shfl (ds_bpermute; wave-uniform delta). Only the 4 needed components are
// shuffled (compile-time R). Invalid dest rows: clamped src row + scale=0.
template <int NB, int R>
__device__ __forceinline__ void p2_batch(const float* __restrict__ xb,
                                         float* __restrict__ ob,
                                         int t0, int wv, int lane, int i0,
                                         int s4, const float* cm, int sy,
                                         float inv, float zoff)
{
    f32x4 v[NB];
    #pragma unroll
    for (int u = 0; u < NB; ++u) {
        const int rr = wv + (t0 + u) * WVB;       // output row in [0, C*H)
        const int j  = rr % kH;                   // wave-uniform scalar
        const int jj = j + sy;
        const int jc = ((unsigned)jj < (unsigned)kH) ? jj : j;  // in-range clamp
        v[u] = *(const f32x4*)(xb + (rr - j + jc) * kW + i0);
    }
    const int ia = lane + s4;                      // src quad q+s4
    const int ib = ia + 1;                         // src quad q+s4+1
    #pragma unroll
    for (int u = 0; u < NB; ++u) {
        const int rr = wv + (t0 + u) * WVB;
        const int j  = rr % kH;
        const int jj = j + sy;
        const float scale = ((unsigned)jj < (unsigned)kH) ? inv : 0.0f;
        f32x4 o;
        #pragma unroll
        for (int k = 0; k < 4; ++k) {
            // element k+R of quad (q+s4) if k+R<4, else element k+R-4 of
            // quad (q+s4+1): one bpermute per output element.
            const float sel = (k + R < 4) ? __shfl(v[u][k + R], ia)
                                          : __shfl(v[u][k + R - 4], ib);
            o[k] = fmaf(sel * cm[k], scale, zoff);  // invalid -> (0-mn)*inv
        }
        *(f32x4*)(ob + rr * kW + i0) = o;         // 16B aligned
    }
}

template <int R>
__device__ __forceinline__ void phase2(const float* __restrict__ xb,
                                       float* __restrict__ ob,
                                       int sy, int sx, float inv, float zoff,
                                       int wv, int lane)
{
    if (lane >= kQPR) return;
    const int i0 = lane * 4;
    const int s4 = (sx - R) >> 2;                  // exact: sx-R multiple of 4

    float cm[4];
    #pragma unroll
    for (int k = 0; k < 4; ++k)
        cm[k] = ((unsigned)(i0 + k + sx) < (unsigned)kW) ? 1.0f : 0.0f;

    for (int t0 = 0; t0 < RPW - 2; t0 += 4)        // 10 batches of 4
        p2_batch<4, R>(xb, ob, t0, wv, lane, i0, s4, cm, sy, inv, zoff);
    p2_batch<2, R>(xb, ob, RPW - 2, wv, lane, i0, s4, cm, sy, inv, zoff);
}

__global__ __launch_bounds__(TB) void shift_norm(
    const float* __restrict__ x, const float* __restrict__ sfy,
    const float* __restrict__ sfx, float* __restrict__ out)
{
    const int img = blockIdx.x;
    const float* __restrict__ xb = x + (size_t)img * kCHW;
    float* __restrict__ ob = out + (size_t)img * kCHW;

    // Replicate reference fp32 order: ((f*2-1)*0.1f)*size, trunc toward zero.
    float ty = sfy[img] * 2.0f - 1.0f; ty *= 0.1f; ty *= (float)kH;
    const int sy = (int)truncf(ty);
    float tx = sfx[img] * 2.0f - 1.0f; tx *= 0.1f; tx *= (float)kW;
    const int sx = (int)truncf(tx);

    // Valid input sub-rectangle (rows/cols of x that survive the shift).
    const int rlo = sy > 0 ? sy : 0;
    const int rhi = kH + (sy < 0 ? sy : 0);
    const int clo = sx > 0 ? sx : 0;
    const int chi = kW + (sx < 0 ? sx : 0);

    const int tid  = threadIdx.x;
    const int lane = tid & 63;
    const int wv   = __builtin_amdgcn_readfirstlane(tid >> 6); // wave-uniform

    // Any nonzero shift introduces zero-fill -> 0 is in the value set, which
    // covers every multiplier-masked (invalid) element's 0 contribution.
    const bool hasfill = (sy != 0) | (sx != 0);
    float vmin = hasfill ? 0.0f : INFINITY;
    float vmax = hasfill ? 0.0f : -INFINITY;

    // ---------------- Phase 1: batched row-wise min/max ----------------
    if (lane < kQPR) {
        const int i0 = lane * 4;
        float cm[4];                      // loop-invariant column validity
        #pragma unroll
        for (int k = 0; k < 4; ++k)
            cm[k] = ((i0 + k) >= clo && (i0 + k) < chi) ? 1.0f : 0.0f;

        for (int t0 = 0; t0 < RPW - 2; t0 += 8)    // 5 batches of 8
            p1_batch<8>(xb, t0, wv, i0, cm, rlo, rhi, vmin, vmax);
        p1_batch<2>(xb, RPW - 2, wv, i0, cm, rlo, rhi, vmin, vmax);
    }

    // Wave (64-lane) shuffle reduction, then cross-wave via LDS.
    #pragma unroll
    for (int off = 32; off > 0; off >>= 1) {
        vmin = fminf(vmin, __shfl_down(vmin, off));
        vmax = fmaxf(vmax, __shfl_down(vmax, off));
    }
    __shared__ float smin[WVB], smax[WVB];
    __shared__ float s_mn, s_inv;
    if (lane == 0) { smin[tid >> 6] = vmin; smax[tid >> 6] = vmax; }
    __syncthreads();
    if (tid == 0) {
        float mn = smin[0], mx = smax[0];
        #pragma unroll
        for (int w = 1; w < WVB; ++w) {
            mn = fminf(mn, smin[w]);
            mx = fmaxf(mx, smax[w]);
        }
        s_mn  = mn;
        s_inv = 1.0f / (mx - mn);
    }
    __syncthreads();
    const float mn   = s_mn;
    const float inv  = s_inv;
    const float zoff = (0.0f - mn) * inv;

    // ---------------- Phase 2: shuffle-gather + normalize + store ----------------
    switch (sx & 3) {
        case 0: phase2<0>(xb, ob, sy, sx, inv, zoff, wv, lane); break;
        case 1: phase2<1>(xb, ob, sy, sx, inv, zoff, wv, lane); break;
        case 2: phase2<2>(xb, ob, sy, sx, inv, zoff, wv, lane); break;
        default: phase2<3>(xb, ob, sy, sx, inv, zoff, wv, lane); break;
    }
}

extern "C" void kernel_launch(void* const* d_in, const int* in_sizes, int n_in,
                              void* d_out, int out_size, void* d_ws, size_t ws_size,
                              hipStream_t stream) {
    const float* x  = (const float*)d_in[0];
    const float* fy = (const float*)d_in[1];
    const float* fx = (const float*)d_in[2];
    float* out = (float*)d_out;
    const int B = in_sizes[1];  // shift_fy has one element per image
    shift_norm<<<B, TB, 0, stream>>>(x, fy, fx, out);
}